// Round 2
// 320.368 us; speedup vs baseline: 1.0282x; 1.0282x over previous
//
#include <hip/hip_runtime.h>

typedef unsigned int uint;
typedef __attribute__((ext_vector_type(8))) short bf16x8;
typedef __attribute__((ext_vector_type(4))) float f32x4;

#define D_IN 128
#define D_H  128
#define D_OUT 16
#define NPC 512                // nodes per coarse bucket
#define NPCSH 9
#define CLDS 224               // >= C = ceil(N/NPC) = 196
#define P1 256                 // pass-1 blocks
#define XL_STRIDE 68
#define WT_STRIDE 68

static __device__ __forceinline__ float bflo(uint u) { return __uint_as_float(u << 16); }
static __device__ __forceinline__ float bfhi(uint u) { return __uint_as_float(u & 0xFFFF0000u); }
static __device__ __forceinline__ uint f2bf(float f) {
    uint b = __float_as_uint(f);
    return (b + 0x7FFFu + ((b >> 16) & 1u)) >> 16;  // RNE
}
static __device__ __forceinline__ uint pk(float a, float b) {
    return f2bf(a) | (f2bf(b) << 16);
}

// ---- pass 1: coarse histogram (private LDS, no global atomics) -------------

__global__ __launch_bounds__(256) void k_p1hist(const int* __restrict__ dst, int E, int N, int C,
                                                int chunk, int* __restrict__ hist1) {
    __shared__ int h[CLDS];
    int t = threadIdx.x, b = blockIdx.x;
    for (int i = t; i < C; i += 256) h[i] = 0;
    __syncthreads();
    int e0 = b * chunk, e1 = min(e0 + chunk, E);
    for (int e = e0 + t; e < e1; e += 256) {
        int d = dst[e];
        d = max(0, min(d, N - 1));
        atomicAdd(&h[d >> NPCSH], 1);
    }
    __syncthreads();
    int* hg = hist1 + (size_t)b * C;
    for (int i = t; i < C; i += 256) hg[i] = h[i];
}

// fused: column sums -> exclusive scan -> convert hist1 to per-(block,bucket) cursors
__global__ __launch_bounds__(1024) void k_p1scan(int* __restrict__ hist1, int C,
                                                 int* __restrict__ cbase) {
    __shared__ int col[CLDS];
    __shared__ int sdata[1024];
    int t = threadIdx.x;
    for (int i = t; i < C; i += 1024) {
        int sum = 0;
        for (int b = 0; b < P1; b++) sum += hist1[(size_t)b * C + i];
        col[i] = sum;
    }
    __syncthreads();
    int v = (t < C) ? col[t] : 0;
    sdata[t] = v;
    __syncthreads();
    for (int off = 1; off < 1024; off <<= 1) {
        int x = (t >= off) ? sdata[t - off] : 0;
        __syncthreads();
        sdata[t] += x;
        __syncthreads();
    }
    int pos = sdata[t] - v;  // exclusive
    if (t < C) cbase[t] = pos;
    if (t == 1023) cbase[C] = sdata[1023];
    if (t < C) {
        int run = pos;
        for (int b = 0; b < P1; b++) {
            size_t idx = (size_t)b * C + t;
            int c = hist1[idx];
            hist1[idx] = run;
            run += c;
        }
    }
}

// scatter packed (dst_local_coarse<<17 | src) into coarse regions, LDS cursors only
__global__ __launch_bounds__(256) void k_p1fill(const int* __restrict__ src,
                                                const int* __restrict__ dst, int E, int N, int C,
                                                int chunk, const int* __restrict__ hist1,
                                                uint* __restrict__ binned1) {
    __shared__ int cur[CLDS];
    int t = threadIdx.x, b = blockIdx.x;
    const int* hg = hist1 + (size_t)b * C;
    for (int i = t; i < C; i += 256) cur[i] = hg[i];
    __syncthreads();
    int e0 = b * chunk, e1 = min(e0 + chunk, E);
    for (int e = e0 + t; e < e1; e += 256) {
        int d = dst[e];
        d = max(0, min(d, N - 1));
        int s = src[e];
        s = max(0, min(s, N - 1));
        int p = atomicAdd(&cur[d >> NPCSH], 1);
        binned1[p] = ((uint)(d & (NPC - 1)) << 17) | (uint)s;
    }
}

// pass 2: one block per coarse bucket -> per-node CSR (rowptr/deg/dinv) + sorted ssrc
__global__ __launch_bounds__(256) void k_p2(const uint* __restrict__ binned1,
                                            const int* __restrict__ cbase, int N,
                                            int* __restrict__ ssrc, int* __restrict__ rowptr,
                                            int* __restrict__ deg, float* __restrict__ dinv) {
    __shared__ int ncnt[NPC], nbase_[NPC];
    __shared__ int sdata[256];
    int c = blockIdx.x, t = threadIdx.x;
    int start = cbase[c], end = cbase[c + 1];
    for (int i = t; i < NPC; i += 256) ncnt[i] = 0;
    __syncthreads();
    for (int j = start + t; j < end; j += 256) atomicAdd(&ncnt[binned1[j] >> 17], 1);
    __syncthreads();
    // parallel exclusive scan, 2 elements per thread (order-preserving)
    int v0 = ncnt[2 * t], v1 = ncnt[2 * t + 1];
    int s = v0 + v1;
    sdata[t] = s;
    __syncthreads();
    for (int off = 1; off < 256; off <<= 1) {
        int xv = (t >= off) ? sdata[t - off] : 0;
        __syncthreads();
        sdata[t] += xv;
        __syncthreads();
    }
    int pre = sdata[t] - s;
    nbase_[2 * t] = start + pre;
    nbase_[2 * t + 1] = start + pre + v0;
    __syncthreads();
    for (int i = t; i < NPC; i += 256) {
        int node = c * NPC + i;
        if (node < N) {
            deg[node] = ncnt[i];
            rowptr[node] = nbase_[i];
            dinv[node] = rsqrtf((float)ncnt[i] + 1.0f);
        }
    }
    __syncthreads();
    for (int i = t; i < NPC; i += 256) ncnt[i] = nbase_[i];  // reuse as cursors
    __syncthreads();
    for (int j = start + t; j < end; j += 256) {
        uint pe = binned1[j];
        int p = atomicAdd(&ncnt[pe >> 17], 1);
        ssrc[p] = (int)(pe & 0x1FFFFu);
    }
}

// ---- GEMM1 (MFMA): hs_b = bf16( dinv[i] * (x @ W1) ) -----------------------
// block: 64 rows x 128 cols. wave w: col-tiles {2w,2w+1}, all 4 row-tiles.
// A frag: A[m=lane&15][k=(lane>>4)*8+j]; B frag: B[k=(lane>>4)*8+j][n=lane&15];
// D: row=(lane>>4)*4+r, col=lane&15.

__global__ __launch_bounds__(256) void k_gemm1(const float* __restrict__ x,
                                               const float* __restrict__ W1,
                                               const float* __restrict__ dinv, int N,
                                               uint* __restrict__ hs_b) {
    __shared__ uint Wt[128 * WT_STRIDE];  // [f][k2] bf16 pairs, 34.8 KB
    __shared__ uint xl[64 * XL_STRIDE];   // [row][k2] bf16 pairs, 17.4 KB; reused as out
    int t = threadIdx.x;
    int row0 = blockIdx.x * 64;
    // stage W1 transposed as bf16 pairs
    for (int p = t; p < 64 * 128; p += 256) {
        int k2 = p >> 7, f = p & 127;
        float w0 = W1[(size_t)(2 * k2) * 128 + f];
        float w1 = W1[(size_t)(2 * k2 + 1) * 128 + f];
        Wt[f * WT_STRIDE + k2] = pk(w0, w1);
    }
    // stage x rows as bf16 pairs
    const float2* x2 = (const float2*)x;
    for (int p = t; p < 64 * 64; p += 256) {
        int r = p >> 6, c = p & 63;
        int gr = row0 + r;
        float2 v = (gr < N) ? x2[(size_t)gr * 64 + c] : make_float2(0.f, 0.f);
        xl[r * XL_STRIDE + c] = pk(v.x, v.y);
    }
    __syncthreads();
    int w = t >> 6, lane = t & 63;
    int q = lane >> 4, m = lane & 15;
    // preload all A fragments (xl dead afterwards)
    bf16x8 afr[4][4];
#pragma unroll
    for (int rt = 0; rt < 4; rt++)
#pragma unroll
        for (int kc = 0; kc < 4; kc++)
            afr[rt][kc] = *(const bf16x8*)&xl[(rt * 16 + m) * XL_STRIDE + kc * 16 + q * 4];
    f32x4 acc[2][4];
#pragma unroll
    for (int c = 0; c < 2; c++)
#pragma unroll
        for (int rt = 0; rt < 4; rt++) acc[c][rt] = (f32x4){0.f, 0.f, 0.f, 0.f};
#pragma unroll
    for (int c = 0; c < 2; c++) {
        int f = w * 32 + c * 16 + m;
#pragma unroll
        for (int kc = 0; kc < 4; kc++) {
            bf16x8 bfr = *(const bf16x8*)&Wt[f * WT_STRIDE + kc * 16 + q * 4];
#pragma unroll
            for (int rt = 0; rt < 4; rt++)
                acc[c][rt] =
                    __builtin_amdgcn_mfma_f32_16x16x32_bf16(afr[rt][kc], bfr, acc[c][rt], 0, 0, 0);
        }
    }
    __syncthreads();  // all waves done reading xl
    uint* outl = xl;  // 64 x 65 packed out tile
#pragma unroll
    for (int rt = 0; rt < 4; rt++) {
        int gb = row0 + rt * 16 + q * 4;
        float4 dv;
        if (gb + 3 < N) {
            dv = *(const float4*)&dinv[gb];
        } else {
            dv.x = (gb < N) ? dinv[gb] : 0.f;
            dv.y = (gb + 1 < N) ? dinv[gb + 1] : 0.f;
            dv.z = (gb + 2 < N) ? dinv[gb + 2] : 0.f;
            dv.w = (gb + 3 < N) ? dinv[gb + 3] : 0.f;
        }
        float dr[4] = {dv.x, dv.y, dv.z, dv.w};
#pragma unroll
        for (int c = 0; c < 2; c++) {
            f32x4 a = acc[c][rt];
#pragma unroll
            for (int r = 0; r < 4; r++) {
                float v = a[r] * dr[r];
                float vn = __shfl_xor(v, 1);
                if (!(lane & 1)) {
                    int row = rt * 16 + q * 4 + r;
                    int cp = (w * 32 + c * 16 + m) >> 1;
                    outl[row * 65 + cp] = pk(v, vn);
                }
            }
        }
    }
    __syncthreads();
    for (int p = t; p < 64 * 64; p += 256) {
        int r = p >> 6, cc = p & 63;
        int gr = row0 + r;
        if (gr < N) hs_b[(size_t)gr * 64 + cc] = outl[r * 65 + cc];
    }
}

// ---- AGG1: wave per node, gather-sum bf16 rows, no atomics -----------------
// Index prefetch: one coalesced lane-parallel ssrc load per <=64 neighbors,
// broadcast via __shfl; gathers issued in independent batches of 16 (MLP 4->16,
// ssrc latency removed from the dependency chain). All loop bounds here are
// wave-uniform (one node per wave) -> every __shfl has all 64 lanes active.

__global__ __launch_bounds__(256) void k_agg1(const uint* __restrict__ hs_b,
                                              const int* __restrict__ rowptr,
                                              const int* __restrict__ deg,
                                              const int* __restrict__ ssrc,
                                              const float* __restrict__ dinv,
                                              const float2* __restrict__ b1, int N,
                                              uint* __restrict__ rh_b) {
    int w = threadIdx.x >> 6, lane = threadIdx.x & 63;
    int d = blockIdx.x * 4 + w;
    if (d >= N) return;
    int start = rowptr[d], cnt = deg[d];
    uint sv = hs_b[(size_t)d * 64 + lane];  // self-loop
    float a0 = bflo(sv), a1 = bfhi(sv);
    int base = 0;
    while (base < cnt) {
        int nb = min(cnt - base, 64);
        int idxv = (lane < nb) ? ssrc[start + base + lane] : 0;
        int j = 0;
        for (; j + 16 <= nb; j += 16) {
            uint u[16];
#pragma unroll
            for (int q = 0; q < 16; q++) {
                int i = __shfl(idxv, j + q);
                u[q] = hs_b[(size_t)i * 64 + lane];
            }
#pragma unroll
            for (int q = 0; q < 16; q++) {
                a0 += bflo(u[q]);
                a1 += bfhi(u[q]);
            }
        }
        for (; j + 4 <= nb; j += 4) {
            uint u[4];
#pragma unroll
            for (int q = 0; q < 4; q++) {
                int i = __shfl(idxv, j + q);
                u[q] = hs_b[(size_t)i * 64 + lane];
            }
#pragma unroll
            for (int q = 0; q < 4; q++) {
                a0 += bflo(u[q]);
                a1 += bfhi(u[q]);
            }
        }
        for (; j < nb; j++) {
            int i = __shfl(idxv, j);
            uint u = hs_b[(size_t)i * 64 + lane];
            a0 += bflo(u);
            a1 += bfhi(u);
        }
        base += nb;
    }
    float sc = dinv[d];
    float2 bb = b1[lane];
    rh_b[(size_t)d * 64 + lane] =
        pk(fmaxf(fmaf(a0, sc, bb.x), 0.f), fmaxf(fmaf(a1, sc, bb.y), 0.f));
}

// ---- GEMM2: h2_b = bf16( dinv[i] * (rh @ W2) ), one row per thread ---------

__global__ __launch_bounds__(256) void k_gemm2(const uint* __restrict__ rh_b,
                                               const float* __restrict__ W2,
                                               const float* __restrict__ dinv, int N,
                                               uint* __restrict__ h2_b) {
    __shared__ float Wl[D_H * D_OUT];  // 8 KB
    int t = threadIdx.x;
    for (int i = t; i < D_H * D_OUT; i += 256) Wl[i] = W2[i];
    __syncthreads();
    int r = blockIdx.x * 256 + t;
    if (r >= N) return;
    const uint* xrow = rh_b + (size_t)r * 64;
    float acc[16];
#pragma unroll
    for (int f = 0; f < 16; f++) acc[f] = 0.f;
    for (int c = 0; c < 16; c++) {
        uint4 xv = *(const uint4*)(xrow + c * 4);
        uint xs[4] = {xv.x, xv.y, xv.z, xv.w};
#pragma unroll
        for (int u = 0; u < 4; u++) {
            int k = c * 8 + u * 2;
            float x0 = bflo(xs[u]), x1 = bfhi(xs[u]);
            const float* w0 = &Wl[k * 16];
            const float* w1 = &Wl[(k + 1) * 16];
#pragma unroll
            for (int f = 0; f < 16; f++) acc[f] = fmaf(x0, w0[f], acc[f]);
#pragma unroll
            for (int f = 0; f < 16; f++) acc[f] = fmaf(x1, w1[f], acc[f]);
        }
    }
    float sc = dinv[r];
    uint o[8];
#pragma unroll
    for (int q = 0; q < 8; q++) o[q] = pk(acc[2 * q] * sc, acc[2 * q + 1] * sc);
    *(uint4*)&h2_b[(size_t)r * 8] = make_uint4(o[0], o[1], o[2], o[3]);
    *(uint4*)&h2_b[(size_t)r * 8 + 4] = make_uint4(o[4], o[5], o[6], o[7]);
}

// ---- AGG2: wave per node (8 edge slots x 8 uint-features), shfl reduce -----
// Index prefetch with a WAVE-UNIFORM group loop: ngroups = ceil(nb/8) is the
// same for all lanes, so every __shfl executes with all 64 lanes active
// (previous round's bug: shfl inside a per-lane-divergent loop pulled from
// exec-masked-off lanes -> undefined data). Only the load/accumulate is
// predicated by j < nb. Source lane j = g*8+slot <= 63 always; lanes >= nb
// hold idx 0 (a valid node) but their values are never accumulated.

__global__ __launch_bounds__(256) void k_agg2(const uint* __restrict__ h2_b,
                                              const int* __restrict__ rowptr,
                                              const int* __restrict__ deg,
                                              const int* __restrict__ ssrc,
                                              const float* __restrict__ dinv,
                                              const float* __restrict__ b2, int N,
                                              float2* __restrict__ out) {
    int w = threadIdx.x >> 6, lane = threadIdx.x & 63;
    int d = blockIdx.x * 4 + w;
    if (d >= N) return;
    int slot = lane >> 3, jp = lane & 7;
    int start = rowptr[d], cnt = deg[d];
    float a0 = 0.f, a1 = 0.f;
    if (slot == 0) {
        uint sv = h2_b[(size_t)d * 8 + jp];  // self-loop
        a0 = bflo(sv);
        a1 = bfhi(sv);
    }
    int base = 0;
    while (base < cnt) {
        int nb = min(cnt - base, 64);
        int idxv = (lane < nb) ? ssrc[start + base + lane] : 0;
        int ngroups = (nb + 7) >> 3;  // wave-uniform
        for (int g = 0; g < ngroups; g++) {
            int j = g * 8 + slot;          // <= 63 always
            int i = __shfl(idxv, j);       // all lanes active here
            if (j < nb) {
                uint hv = h2_b[(size_t)i * 8 + jp];
                a0 += bflo(hv);
                a1 += bfhi(hv);
            }
        }
        base += nb;
    }
    a0 += __shfl_xor(a0, 8);
    a1 += __shfl_xor(a1, 8);
    a0 += __shfl_xor(a0, 16);
    a1 += __shfl_xor(a1, 16);
    a0 += __shfl_xor(a0, 32);
    a1 += __shfl_xor(a1, 32);
    if (slot == 0) {
        float di = dinv[d];
        out[(size_t)d * 8 + jp] =
            make_float2(fmaf(a0, di, b2[2 * jp]), fmaf(a1, di, b2[2 * jp + 1]));
    }
}

// ---- launch ----------------------------------------------------------------

extern "C" void kernel_launch(void* const* d_in, const int* in_sizes, int n_in,
                              void* d_out, int out_size, void* d_ws, size_t ws_size,
                              hipStream_t stream) {
    const float* x  = (const float*)d_in[0];
    const int*   ei = (const int*)d_in[1];
    const float* W1 = (const float*)d_in[2];
    const float* b1 = (const float*)d_in[3];
    const float* W2 = (const float*)d_in[4];
    const float* b2 = (const float*)d_in[5];
    int N = in_sizes[0] / D_IN;
    int E = in_sizes[1] / 2;
    const int* src = ei;
    const int* dst = ei + E;
    int C = (N + NPC - 1) / NPC;           // 196
    int chunk = (E + P1 - 1) / P1;         // 6250

    char* ws = (char*)d_ws;
    size_t off = 0;
    auto alloc = [&](size_t bytes) -> char* {
        char* p = ws + off;
        off = (off + bytes + 255) & ~(size_t)255;
        return p;
    };
    int*   hist1   = (int*)alloc((size_t)P1 * C * 4);
    int*   cbase   = (int*)alloc((size_t)(C + 1) * 4);
    uint*  binned1 = (uint*)alloc((size_t)E * 4);
    int*   ssrc    = (int*)alloc((size_t)E * 4);
    int*   rowptr  = (int*)alloc((size_t)N * 4);
    int*   deg     = (int*)alloc((size_t)N * 4);
    float* dinv    = (float*)alloc((size_t)N * 4);
    uint*  hs_b    = (uint*)alloc((size_t)N * 64 * 4);      // 25.6 MB bf16-packed
    uint*  rh_b    = (uint*)alloc((size_t)N * 64 * 4);
    uint*  h2_b    = hs_b;  // hs_b dead after k_agg1; reuse

    k_p1hist<<<P1, 256, 0, stream>>>(dst, E, N, C, chunk, hist1);
    k_p1scan<<<1, 1024, 0, stream>>>(hist1, C, cbase);
    k_p1fill<<<P1, 256, 0, stream>>>(src, dst, E, N, C, chunk, hist1, binned1);
    k_p2<<<C, 256, 0, stream>>>(binned1, cbase, N, ssrc, rowptr, deg, dinv);
    k_gemm1<<<(N + 63) / 64, 256, 0, stream>>>(x, W1, dinv, N, hs_b);
    k_agg1<<<(N + 3) / 4, 256, 0, stream>>>(hs_b, rowptr, deg, ssrc, dinv,
                                            (const float2*)b1, N, rh_b);
    k_gemm2<<<(N + 255) / 256, 256, 0, stream>>>(rh_b, W2, dinv, N, h2_b);
    k_agg2<<<(N + 3) / 4, 256, 0, stream>>>(h2_b, rowptr, deg, ssrc, dinv, b2, N,
                                            (float2*)d_out);
}

// Round 3
// 295.130 us; speedup vs baseline: 1.1161x; 1.0855x over previous
//
#include <hip/hip_runtime.h>

typedef unsigned int uint;
typedef __attribute__((ext_vector_type(8))) short bf16x8;
typedef __attribute__((ext_vector_type(4))) float f32x4;

#define D_IN 128
#define D_H  128
#define D_OUT 16
#define NPC 512                // nodes per coarse bucket
#define NPCSH 9
#define CLDS 224               // >= C = ceil(N/NPC) = 196
#define P1 256                 // pass-1 blocks
#define XL_STRIDE 68
#define WT_STRIDE 68

static __device__ __forceinline__ float bflo(uint u) { return __uint_as_float(u << 16); }
static __device__ __forceinline__ float bfhi(uint u) { return __uint_as_float(u & 0xFFFF0000u); }
static __device__ __forceinline__ uint f2bf(float f) {
    uint b = __float_as_uint(f);
    return (b + 0x7FFFu + ((b >> 16) & 1u)) >> 16;  // RNE
}
static __device__ __forceinline__ uint pk(float a, float b) {
    return f2bf(a) | (f2bf(b) << 16);
}

// ---- pass 1: coarse histogram (private LDS, no global atomics) -------------
// hist1 layout is TRANSPOSED: hist1[bucket * P1 + block] so k_p1scan can scan
// each bucket's 256 per-block counts with one coalesced wave.

__global__ __launch_bounds__(256) void k_p1hist(const int* __restrict__ dst, int E, int N, int C,
                                                int chunk, int* __restrict__ hist1) {
    __shared__ int h[CLDS];
    int t = threadIdx.x, b = blockIdx.x;
    for (int i = t; i < C; i += 256) h[i] = 0;
    __syncthreads();
    int e0 = b * chunk, e1 = min(e0 + chunk, E);
    for (int e = e0 + t; e < e1; e += 256) {
        int d = dst[e];
        d = max(0, min(d, N - 1));
        atomicAdd(&h[d >> NPCSH], 1);
    }
    __syncthreads();
    for (int i = t; i < C; i += 256) hist1[(size_t)i * P1 + b] = h[i];
}

// wave-parallel: per-bucket wave scan (int4/lane over 256 counts) -> local
// prefixes; block scan over bucket totals -> cbase; add base back per bucket.
__global__ __launch_bounds__(1024) void k_p1scan(int* __restrict__ hist1, int C,
                                                 int* __restrict__ cbase) {
    __shared__ int col[CLDS];
    __shared__ int sdata[1024];
    int t = threadIdx.x;
    int w = t >> 6, lane = t & 63;
    // Phase A: each wave scans whole buckets (coalesced int4 loads)
    for (int i = w; i < C; i += 16) {
        int4 v = ((const int4*)hist1)[i * 64 + lane];
        int s = v.x + v.y + v.z + v.w;
        int inc = s;
        for (int off = 1; off < 64; off <<= 1) {
            int o = __shfl_up(inc, off);
            if (lane >= off) inc += o;
        }
        int excl = inc - s;
        int4 p;
        p.x = excl;
        p.y = excl + v.x;
        p.z = excl + v.x + v.y;
        p.w = excl + v.x + v.y + v.z;
        ((int4*)hist1)[i * 64 + lane] = p;  // local (bucket-relative) cursors
        if (lane == 63) col[i] = inc;       // bucket total
    }
    __syncthreads();
    // Phase B: block scan over C bucket totals
    int v = (t < C) ? col[t] : 0;
    sdata[t] = v;
    __syncthreads();
    for (int off = 1; off < 1024; off <<= 1) {
        int x = (t >= off) ? sdata[t - off] : 0;
        __syncthreads();
        sdata[t] += x;
        __syncthreads();
    }
    int pos = sdata[t] - v;  // exclusive
    if (t < C) cbase[t] = pos;
    if (t == 1023) cbase[C] = sdata[1023];
    if (t < C) col[t] = pos;  // bucket base for phase C
    __syncthreads();
    // Phase C: same wave owns same buckets -> add bucket base to local cursors
    for (int i = w; i < C; i += 16) {
        int base = col[i];
        int4 p = ((int4*)hist1)[i * 64 + lane];
        p.x += base; p.y += base; p.z += base; p.w += base;
        ((int4*)hist1)[i * 64 + lane] = p;
    }
}

// scatter packed (dst_local_coarse<<17 | src) into coarse regions, LDS cursors only
__global__ __launch_bounds__(256) void k_p1fill(const int* __restrict__ src,
                                                const int* __restrict__ dst, int E, int N, int C,
                                                int chunk, const int* __restrict__ hist1,
                                                uint* __restrict__ binned1) {
    __shared__ int cur[CLDS];
    int t = threadIdx.x, b = blockIdx.x;
    for (int i = t; i < C; i += 256) cur[i] = hist1[(size_t)i * P1 + b];
    __syncthreads();
    int e0 = b * chunk, e1 = min(e0 + chunk, E);
    for (int e = e0 + t; e < e1; e += 256) {
        int d = dst[e];
        d = max(0, min(d, N - 1));
        int s = src[e];
        s = max(0, min(s, N - 1));
        int p = atomicAdd(&cur[d >> NPCSH], 1);
        binned1[p] = ((uint)(d & (NPC - 1)) << 17) | (uint)s;
    }
}

// pass 2: one block per coarse bucket -> per-node CSR (rowptr/deg/dinv) + sorted ssrc
__global__ __launch_bounds__(256) void k_p2(const uint* __restrict__ binned1,
                                            const int* __restrict__ cbase, int N,
                                            int* __restrict__ ssrc, int* __restrict__ rowptr,
                                            int* __restrict__ deg, float* __restrict__ dinv) {
    __shared__ int ncnt[NPC], nbase_[NPC];
    __shared__ int sdata[256];
    int c = blockIdx.x, t = threadIdx.x;
    int start = cbase[c], end = cbase[c + 1];
    for (int i = t; i < NPC; i += 256) ncnt[i] = 0;
    __syncthreads();
    for (int j = start + t; j < end; j += 256) atomicAdd(&ncnt[binned1[j] >> 17], 1);
    __syncthreads();
    // parallel exclusive scan, 2 elements per thread (order-preserving)
    int v0 = ncnt[2 * t], v1 = ncnt[2 * t + 1];
    int s = v0 + v1;
    sdata[t] = s;
    __syncthreads();
    for (int off = 1; off < 256; off <<= 1) {
        int xv = (t >= off) ? sdata[t - off] : 0;
        __syncthreads();
        sdata[t] += xv;
        __syncthreads();
    }
    int pre = sdata[t] - s;
    nbase_[2 * t] = start + pre;
    nbase_[2 * t + 1] = start + pre + v0;
    __syncthreads();
    for (int i = t; i < NPC; i += 256) {
        int node = c * NPC + i;
        if (node < N) {
            deg[node] = ncnt[i];
            rowptr[node] = nbase_[i];
            dinv[node] = rsqrtf((float)ncnt[i] + 1.0f);
        }
    }
    __syncthreads();
    for (int i = t; i < NPC; i += 256) ncnt[i] = nbase_[i];  // reuse as cursors
    __syncthreads();
    for (int j = start + t; j < end; j += 256) {
        uint pe = binned1[j];
        int p = atomicAdd(&ncnt[pe >> 17], 1);
        ssrc[p] = (int)(pe & 0x1FFFFu);
    }
}

// ---- W1 pre-pack: W1p[k2*128 + f] = pk(W1[2k2][f], W1[2k2+1][f]) -----------

__global__ __launch_bounds__(256) void k_packW1(const float* __restrict__ W1,
                                                uint* __restrict__ W1p) {
    int t = blockIdx.x * 256 + threadIdx.x;
    if (t >= 64 * 128) return;
    int k2 = t >> 7, f = t & 127;  // consecutive t -> consecutive f: coalesced
    float w0 = W1[(size_t)(2 * k2) * 128 + f];
    float w1 = W1[(size_t)(2 * k2 + 1) * 128 + f];
    W1p[t] = pk(w0, w1);
}

// ---- GEMM1 (MFMA, persistent): hs_b = bf16( dinv[i] * (x @ W1) ) -----------
// 768 blocks (3/CU by LDS), Wt staged ONCE per block from packed W1p, then
// grid-stride over 64-row tiles. W1 global traffic: 1563x64KB -> 768x32KB.
// block: 64 rows x 128 cols. wave w: col-tiles {2w,2w+1}, all 4 row-tiles.

__global__ __launch_bounds__(256) void k_gemm1(const uint* __restrict__ W1p,
                                               const float* __restrict__ x,
                                               const float* __restrict__ dinv, int N,
                                               uint* __restrict__ hs_b, int ntiles) {
    __shared__ uint Wt[128 * WT_STRIDE];  // [f][k2] bf16 pairs, 34.8 KB
    __shared__ uint xl[64 * XL_STRIDE];   // [row][k2] bf16 pairs, 17.4 KB; reused as out
    int t = threadIdx.x;
    for (int p = t; p < 64 * 128; p += 256) {
        int k2 = p >> 7, f = p & 127;
        Wt[f * WT_STRIDE + k2] = W1p[p];
    }
    int w = t >> 6, lane = t & 63;
    int q = lane >> 4, m = lane & 15;
    const float4* x4 = (const float4*)x;
    for (int tile = blockIdx.x; tile < ntiles; tile += gridDim.x) {
        int row0 = tile * 64;
        __syncthreads();  // Wt ready (iter 0) / outl fully drained (iters > 0)
        for (int p = t; p < 64 * 32; p += 256) {
            int r = p >> 5, c2 = p & 31;
            int gr = row0 + r;
            float4 v = (gr < N) ? x4[(size_t)gr * 32 + c2] : make_float4(0.f, 0.f, 0.f, 0.f);
            *(uint2*)&xl[r * XL_STRIDE + 2 * c2] = make_uint2(pk(v.x, v.y), pk(v.z, v.w));
        }
        __syncthreads();
        // preload all A fragments (xl dead afterwards)
        bf16x8 afr[4][4];
#pragma unroll
        for (int rt = 0; rt < 4; rt++)
#pragma unroll
            for (int kc = 0; kc < 4; kc++)
                afr[rt][kc] = *(const bf16x8*)&xl[(rt * 16 + m) * XL_STRIDE + kc * 16 + q * 4];
        f32x4 acc[2][4];
#pragma unroll
        for (int c = 0; c < 2; c++)
#pragma unroll
            for (int rt = 0; rt < 4; rt++) acc[c][rt] = (f32x4){0.f, 0.f, 0.f, 0.f};
#pragma unroll
        for (int c = 0; c < 2; c++) {
            int f = w * 32 + c * 16 + m;
#pragma unroll
            for (int kc = 0; kc < 4; kc++) {
                bf16x8 bfr = *(const bf16x8*)&Wt[f * WT_STRIDE + kc * 16 + q * 4];
#pragma unroll
                for (int rt = 0; rt < 4; rt++)
                    acc[c][rt] = __builtin_amdgcn_mfma_f32_16x16x32_bf16(afr[rt][kc], bfr,
                                                                         acc[c][rt], 0, 0, 0);
            }
        }
        __syncthreads();  // all waves done reading xl
        uint* outl = xl;  // 64 x 65 packed out tile
#pragma unroll
        for (int rt = 0; rt < 4; rt++) {
            int gb = row0 + rt * 16 + q * 4;
            float4 dv;
            if (gb + 3 < N) {
                dv = *(const float4*)&dinv[gb];
            } else {
                dv.x = (gb < N) ? dinv[gb] : 0.f;
                dv.y = (gb + 1 < N) ? dinv[gb + 1] : 0.f;
                dv.z = (gb + 2 < N) ? dinv[gb + 2] : 0.f;
                dv.w = (gb + 3 < N) ? dinv[gb + 3] : 0.f;
            }
            float dr[4] = {dv.x, dv.y, dv.z, dv.w};
#pragma unroll
            for (int c = 0; c < 2; c++) {
                f32x4 a = acc[c][rt];
#pragma unroll
                for (int r = 0; r < 4; r++) {
                    float v = a[r] * dr[r];
                    float vn = __shfl_xor(v, 1);
                    if (!(lane & 1)) {
                        int row = rt * 16 + q * 4 + r;
                        int cp = (w * 32 + c * 16 + m) >> 1;
                        outl[row * 65 + cp] = pk(v, vn);
                    }
                }
            }
        }
        __syncthreads();
        for (int p = t; p < 64 * 64; p += 256) {
            int r = p >> 6, cc = p & 63;
            int gr = row0 + r;
            if (gr < N) hs_b[(size_t)gr * 64 + cc] = outl[r * 65 + cc];
        }
    }
}

// ---- AGG1: wave per node, gather-sum bf16 rows, no atomics -----------------
// (unchanged from passing version: at the cross-XCD L3 service-rate floor)

__global__ __launch_bounds__(256) void k_agg1(const uint* __restrict__ hs_b,
                                              const int* __restrict__ rowptr,
                                              const int* __restrict__ deg,
                                              const int* __restrict__ ssrc,
                                              const float* __restrict__ dinv,
                                              const float2* __restrict__ b1, int N,
                                              uint* __restrict__ rh_b) {
    int w = threadIdx.x >> 6, lane = threadIdx.x & 63;
    int d = blockIdx.x * 4 + w;
    if (d >= N) return;
    int start = rowptr[d], cnt = deg[d];
    uint sv = hs_b[(size_t)d * 64 + lane];  // self-loop
    float a0 = bflo(sv), a1 = bfhi(sv);
    int base = 0;
    while (base < cnt) {
        int nb = min(cnt - base, 64);
        int idxv = (lane < nb) ? ssrc[start + base + lane] : 0;
        int j = 0;
        for (; j + 16 <= nb; j += 16) {
            uint u[16];
#pragma unroll
            for (int q = 0; q < 16; q++) {
                int i = __shfl(idxv, j + q);
                u[q] = hs_b[(size_t)i * 64 + lane];
            }
#pragma unroll
            for (int q = 0; q < 16; q++) {
                a0 += bflo(u[q]);
                a1 += bfhi(u[q]);
            }
        }
        for (; j + 4 <= nb; j += 4) {
            uint u[4];
#pragma unroll
            for (int q = 0; q < 4; q++) {
                int i = __shfl(idxv, j + q);
                u[q] = hs_b[(size_t)i * 64 + lane];
            }
#pragma unroll
            for (int q = 0; q < 4; q++) {
                a0 += bflo(u[q]);
                a1 += bfhi(u[q]);
            }
        }
        for (; j < nb; j++) {
            int i = __shfl(idxv, j);
            uint u = hs_b[(size_t)i * 64 + lane];
            a0 += bflo(u);
            a1 += bfhi(u);
        }
        base += nb;
    }
    float sc = dinv[d];
    float2 bb = b1[lane];
    rh_b[(size_t)d * 64 + lane] =
        pk(fmaxf(fmaf(a0, sc, bb.x), 0.f), fmaxf(fmaf(a1, sc, bb.y), 0.f));
}

// ---- GEMM2: h2_b = bf16( dinv[i] * (rh @ W2) ), one row per thread ---------

__global__ __launch_bounds__(256) void k_gemm2(const uint* __restrict__ rh_b,
                                               const float* __restrict__ W2,
                                               const float* __restrict__ dinv, int N,
                                               uint* __restrict__ h2_b) {
    __shared__ float Wl[D_H * D_OUT];  // 8 KB
    int t = threadIdx.x;
    for (int i = t; i < D_H * D_OUT; i += 256) Wl[i] = W2[i];
    __syncthreads();
    int r = blockIdx.x * 256 + t;
    if (r >= N) return;
    const uint* xrow = rh_b + (size_t)r * 64;
    float acc[16];
#pragma unroll
    for (int f = 0; f < 16; f++) acc[f] = 0.f;
    for (int c = 0; c < 16; c++) {
        uint4 xv = *(const uint4*)(xrow + c * 4);
        uint xs[4] = {xv.x, xv.y, xv.z, xv.w};
#pragma unroll
        for (int u = 0; u < 4; u++) {
            int k = c * 8 + u * 2;
            float x0 = bflo(xs[u]), x1 = bfhi(xs[u]);
            const float* w0 = &Wl[k * 16];
            const float* w1 = &Wl[(k + 1) * 16];
#pragma unroll
            for (int f = 0; f < 16; f++) acc[f] = fmaf(x0, w0[f], acc[f]);
#pragma unroll
            for (int f = 0; f < 16; f++) acc[f] = fmaf(x1, w1[f], acc[f]);
        }
    }
    float sc = dinv[r];
    uint o[8];
#pragma unroll
    for (int q = 0; q < 8; q++) o[q] = pk(acc[2 * q] * sc, acc[2 * q + 1] * sc);
    *(uint4*)&h2_b[(size_t)r * 8] = make_uint4(o[0], o[1], o[2], o[3]);
    *(uint4*)&h2_b[(size_t)r * 8 + 4] = make_uint4(o[4], o[5], o[6], o[7]);
}

// ---- AGG2: wave per node (8 edge slots x 8 uint-features), shfl reduce -----
// (unchanged from passing version: wave-uniform group loop for the shfl)

__global__ __launch_bounds__(256) void k_agg2(const uint* __restrict__ h2_b,
                                              const int* __restrict__ rowptr,
                                              const int* __restrict__ deg,
                                              const int* __restrict__ ssrc,
                                              const float* __restrict__ dinv,
                                              const float* __restrict__ b2, int N,
                                              float2* __restrict__ out) {
    int w = threadIdx.x >> 6, lane = threadIdx.x & 63;
    int d = blockIdx.x * 4 + w;
    if (d >= N) return;
    int slot = lane >> 3, jp = lane & 7;
    int start = rowptr[d], cnt = deg[d];
    float a0 = 0.f, a1 = 0.f;
    if (slot == 0) {
        uint sv = h2_b[(size_t)d * 8 + jp];  // self-loop
        a0 = bflo(sv);
        a1 = bfhi(sv);
    }
    int base = 0;
    while (base < cnt) {
        int nb = min(cnt - base, 64);
        int idxv = (lane < nb) ? ssrc[start + base + lane] : 0;
        int ngroups = (nb + 7) >> 3;  // wave-uniform
        for (int g = 0; g < ngroups; g++) {
            int j = g * 8 + slot;          // <= 63 always
            int i = __shfl(idxv, j);       // all lanes active here
            if (j < nb) {
                uint hv = h2_b[(size_t)i * 8 + jp];
                a0 += bflo(hv);
                a1 += bfhi(hv);
            }
        }
        base += nb;
    }
    a0 += __shfl_xor(a0, 8);
    a1 += __shfl_xor(a1, 8);
    a0 += __shfl_xor(a0, 16);
    a1 += __shfl_xor(a1, 16);
    a0 += __shfl_xor(a0, 32);
    a1 += __shfl_xor(a1, 32);
    if (slot == 0) {
        float di = dinv[d];
        out[(size_t)d * 8 + jp] =
            make_float2(fmaf(a0, di, b2[2 * jp]), fmaf(a1, di, b2[2 * jp + 1]));
    }
}

// ---- launch ----------------------------------------------------------------

extern "C" void kernel_launch(void* const* d_in, const int* in_sizes, int n_in,
                              void* d_out, int out_size, void* d_ws, size_t ws_size,
                              hipStream_t stream) {
    const float* x  = (const float*)d_in[0];
    const int*   ei = (const int*)d_in[1];
    const float* W1 = (const float*)d_in[2];
    const float* b1 = (const float*)d_in[3];
    const float* W2 = (const float*)d_in[4];
    const float* b2 = (const float*)d_in[5];
    int N = in_sizes[0] / D_IN;
    int E = in_sizes[1] / 2;
    const int* src = ei;
    const int* dst = ei + E;
    int C = (N + NPC - 1) / NPC;           // 196
    int chunk = (E + P1 - 1) / P1;         // 6250
    int ntiles = (N + 63) / 64;            // 1563

    char* ws = (char*)d_ws;
    size_t off = 0;
    auto alloc = [&](size_t bytes) -> char* {
        char* p = ws + off;
        off = (off + bytes + 255) & ~(size_t)255;
        return p;
    };
    int*   hist1   = (int*)alloc((size_t)P1 * C * 4);
    int*   cbase   = (int*)alloc((size_t)(C + 1) * 4);
    uint*  binned1 = (uint*)alloc((size_t)E * 4);
    int*   ssrc    = (int*)alloc((size_t)E * 4);
    int*   rowptr  = (int*)alloc((size_t)N * 4);
    int*   deg     = (int*)alloc((size_t)N * 4);
    float* dinv    = (float*)alloc((size_t)N * 4);
    uint*  W1p     = (uint*)alloc((size_t)64 * 128 * 4);    // 32 KB packed W1
    uint*  hs_b    = (uint*)alloc((size_t)N * 64 * 4);      // 25.6 MB bf16-packed
    uint*  rh_b    = (uint*)alloc((size_t)N * 64 * 4);
    uint*  h2_b    = hs_b;  // hs_b dead after k_agg1; reuse

    k_packW1<<<32, 256, 0, stream>>>(W1, W1p);
    k_p1hist<<<P1, 256, 0, stream>>>(dst, E, N, C, chunk, hist1);
    k_p1scan<<<1, 1024, 0, stream>>>(hist1, C, cbase);
    k_p1fill<<<P1, 256, 0, stream>>>(src, dst, E, N, C, chunk, hist1, binned1);
    k_p2<<<C, 256, 0, stream>>>(binned1, cbase, N, ssrc, rowptr, deg, dinv);
    int g1 = min(768, ntiles);
    k_gemm1<<<g1, 256, 0, stream>>>(W1p, x, dinv, N, hs_b, ntiles);
    k_agg1<<<(N + 3) / 4, 256, 0, stream>>>(hs_b, rowptr, deg, ssrc, dinv,
                                            (const float2*)b1, N, rh_b);
    k_gemm2<<<(N + 255) / 256, 256, 0, stream>>>(rh_b, W2, dinv, N, h2_b);
    k_agg2<<<(N + 3) / 4, 256, 0, stream>>>(h2_b, rowptr, deg, ssrc, dinv, b2, N,
                                            (float2*)d_out);
}

// Round 5
// 278.470 us; speedup vs baseline: 1.1829x; 1.0598x over previous
//
#include <hip/hip_runtime.h>

typedef unsigned int uint;
typedef __attribute__((ext_vector_type(8))) short bf16x8;
typedef __attribute__((ext_vector_type(4))) float f32x4;

#define D_IN 128
#define D_H  128
#define D_OUT 16
#define NPC 512                // nodes per coarse bucket
#define NPCSH 9
#define CLDS 224               // >= C = ceil(N/NPC) = 196
#define P1 256                 // pass-1 blocks
#define XL_STRIDE 68
#define WT_STRIDE 68

static __device__ __forceinline__ float bflo(uint u) { return __uint_as_float(u << 16); }
static __device__ __forceinline__ float bfhi(uint u) { return __uint_as_float(u & 0xFFFF0000u); }
static __device__ __forceinline__ uint f2bf(float f) {
    uint b = __float_as_uint(f);
    return (b + 0x7FFFu + ((b >> 16) & 1u)) >> 16;  // RNE
}
static __device__ __forceinline__ uint pk(float a, float b) {
    return f2bf(a) | (f2bf(b) << 16);
}

// ---- pass 1: coarse histogram + (fused) W1 pre-pack ------------------------
// blocks [0,P1): histogram (hist1 TRANSPOSED: hist1[bucket*P1 + block]).
// blocks [P1,P1+32): pack W1 -> W1p[k2*128+f] = pk(W1[2k2][f], W1[2k2+1][f]).

__global__ __launch_bounds__(256) void k_p1hist(const int* __restrict__ dst, int E, int N, int C,
                                                int chunk, int* __restrict__ hist1,
                                                const float* __restrict__ W1,
                                                uint* __restrict__ W1p) {
    __shared__ int h[CLDS];
    int t = threadIdx.x, b = blockIdx.x;
    if (b >= P1) {  // W1 pack role
        int p = (b - P1) * 256 + t;  // 32*256 = 8192 = 64*128
        int k2 = p >> 7, f = p & 127;
        float w0 = W1[(size_t)(2 * k2) * 128 + f];
        float w1 = W1[(size_t)(2 * k2 + 1) * 128 + f];
        W1p[p] = pk(w0, w1);
        return;
    }
    for (int i = t; i < C; i += 256) h[i] = 0;
    __syncthreads();
    int e0 = b * chunk, e1 = min(e0 + chunk, E);
    for (int e = e0 + t; e < e1; e += 256) {
        int d = dst[e];
        d = max(0, min(d, N - 1));
        atomicAdd(&h[d >> NPCSH], 1);
    }
    __syncthreads();
    for (int i = t; i < C; i += 256) hist1[(size_t)i * P1 + b] = h[i];
}

// wave-parallel: per-bucket wave scan (int4/lane over 256 counts) -> local
// prefixes; block scan over bucket totals -> cbase; add base back per bucket.
__global__ __launch_bounds__(1024) void k_p1scan(int* __restrict__ hist1, int C,
                                                 int* __restrict__ cbase) {
    __shared__ int col[CLDS];
    __shared__ int sdata[1024];
    int t = threadIdx.x;
    int w = t >> 6, lane = t & 63;
    // Phase A: each wave scans whole buckets (coalesced int4 loads)
    for (int i = w; i < C; i += 16) {
        int4 v = ((const int4*)hist1)[i * 64 + lane];
        int s = v.x + v.y + v.z + v.w;
        int inc = s;
        for (int off = 1; off < 64; off <<= 1) {
            int o = __shfl_up(inc, off);
            if (lane >= off) inc += o;
        }
        int excl = inc - s;
        int4 p;
        p.x = excl;
        p.y = excl + v.x;
        p.z = excl + v.x + v.y;
        p.w = excl + v.x + v.y + v.z;
        ((int4*)hist1)[i * 64 + lane] = p;  // local (bucket-relative) cursors
        if (lane == 63) col[i] = inc;       // bucket total
    }
    __syncthreads();
    // Phase B: block scan over C bucket totals
    int v = (t < C) ? col[t] : 0;
    sdata[t] = v;
    __syncthreads();
    for (int off = 1; off < 1024; off <<= 1) {
        int x = (t >= off) ? sdata[t - off] : 0;
        __syncthreads();
        sdata[t] += x;
        __syncthreads();
    }
    int pos = sdata[t] - v;  // exclusive
    if (t < C) cbase[t] = pos;
    if (t == 1023) cbase[C] = sdata[1023];
    if (t < C) col[t] = pos;  // bucket base for phase C
    __syncthreads();
    // Phase C: same wave owns same buckets -> add bucket base to local cursors
    for (int i = w; i < C; i += 16) {
        int base = col[i];
        int4 p = ((int4*)hist1)[i * 64 + lane];
        p.x += base; p.y += base; p.z += base; p.w += base;
        ((int4*)hist1)[i * 64 + lane] = p;
    }
}

// scatter packed (dst_local_coarse<<17 | src) into coarse regions, LDS cursors only
__global__ __launch_bounds__(256) void k_p1fill(const int* __restrict__ src,
                                                const int* __restrict__ dst, int E, int N, int C,
                                                int chunk, const int* __restrict__ hist1,
                                                uint* __restrict__ binned1) {
    __shared__ int cur[CLDS];
    int t = threadIdx.x, b = blockIdx.x;
    for (int i = t; i < C; i += 256) cur[i] = hist1[(size_t)i * P1 + b];
    __syncthreads();
    int e0 = b * chunk, e1 = min(e0 + chunk, E);
    for (int e = e0 + t; e < e1; e += 256) {
        int d = dst[e];
        d = max(0, min(d, N - 1));
        int s = src[e];
        s = max(0, min(s, N - 1));
        int p = atomicAdd(&cur[d >> NPCSH], 1);
        binned1[p] = ((uint)(d & (NPC - 1)) << 17) | (uint)s;
    }
}

// ---- fused: p2 (fine CSR sort) PARALLEL WITH gemm1 (MFMA, persistent) ------
// blocks [0,C): p2 role -- per-node CSR (rowptr/deg/dinv) + sorted ssrc.
// blocks [C, C+768): gemm1 role -- hs_b = bf16(x @ W1), UNSCALED (dinv applied
// in k_agg1), so gemm1 has no dependency on p2 and overlaps it fully.
// LDS is a union: gemm1 needs 52224 B (Wt 128x68 + xl 64x68 uints); p2 needs
// 5120 B (ncnt/nbase_/sdata) carved from the same buffer -> 3 blocks/CU both.

__global__ __launch_bounds__(256) void k_p2gemm1(const uint* __restrict__ binned1,
                                                 const int* __restrict__ cbase, int N, int C,
                                                 int* __restrict__ ssrc, int* __restrict__ rowptr,
                                                 int* __restrict__ deg, float* __restrict__ dinv,
                                                 const uint* __restrict__ W1p,
                                                 const float* __restrict__ x,
                                                 uint* __restrict__ hs_b, int ntiles) {
    __shared__ uint smem[128 * WT_STRIDE + 64 * XL_STRIDE];  // 52224 B
    int t = threadIdx.x;
    if ((int)blockIdx.x < C) {
        // ---------------- p2 role ----------------
        int* ncnt = (int*)smem;
        int* nbase_ = ncnt + NPC;
        int* sdata = nbase_ + NPC;
        int c = blockIdx.x;
        int start = cbase[c], end = cbase[c + 1];
        for (int i = t; i < NPC; i += 256) ncnt[i] = 0;
        __syncthreads();
        for (int j = start + t; j < end; j += 256) atomicAdd(&ncnt[binned1[j] >> 17], 1);
        __syncthreads();
        // parallel exclusive scan, 2 elements per thread (order-preserving)
        int v0 = ncnt[2 * t], v1 = ncnt[2 * t + 1];
        int s = v0 + v1;
        sdata[t] = s;
        __syncthreads();
        for (int off = 1; off < 256; off <<= 1) {
            int xv = (t >= off) ? sdata[t - off] : 0;
            __syncthreads();
            sdata[t] += xv;
            __syncthreads();
        }
        int pre = sdata[t] - s;
        nbase_[2 * t] = start + pre;
        nbase_[2 * t + 1] = start + pre + v0;
        __syncthreads();
        for (int i = t; i < NPC; i += 256) {
            int node = c * NPC + i;
            if (node < N) {
                deg[node] = ncnt[i];
                rowptr[node] = nbase_[i];
                dinv[node] = rsqrtf((float)ncnt[i] + 1.0f);
            }
        }
        __syncthreads();
        for (int i = t; i < NPC; i += 256) ncnt[i] = nbase_[i];  // reuse as cursors
        __syncthreads();
        for (int j = start + t; j < end; j += 256) {
            uint pe = binned1[j];
            int p = atomicAdd(&ncnt[pe >> 17], 1);
            ssrc[p] = (int)(pe & 0x1FFFFu);
        }
        return;
    }
    // ---------------- gemm1 role ----------------
    uint* Wt = smem;                        // [f][k2] bf16 pairs
    uint* xl = smem + 128 * WT_STRIDE;      // [row][k2] bf16 pairs; reused as out
    int role = blockIdx.x - C;
    int nroles = gridDim.x - C;
    for (int p = t; p < 64 * 128; p += 256) {
        int k2 = p >> 7, f = p & 127;
        Wt[f * WT_STRIDE + k2] = W1p[p];
    }
    int w = t >> 6, lane = t & 63;
    int q = lane >> 4, m = lane & 15;
    const float4* x4 = (const float4*)x;
    for (int tile = role; tile < ntiles; tile += nroles) {
        int row0 = tile * 64;
        __syncthreads();  // Wt ready (iter 0) / outl fully drained (iters > 0)
        for (int p = t; p < 64 * 32; p += 256) {
            int r = p >> 5, c2 = p & 31;
            int gr = row0 + r;
            float4 v = (gr < N) ? x4[(size_t)gr * 32 + c2] : make_float4(0.f, 0.f, 0.f, 0.f);
            *(uint2*)&xl[r * XL_STRIDE + 2 * c2] = make_uint2(pk(v.x, v.y), pk(v.z, v.w));
        }
        __syncthreads();
        // preload all A fragments (xl dead afterwards)
        bf16x8 afr[4][4];
#pragma unroll
        for (int rt = 0; rt < 4; rt++)
#pragma unroll
            for (int kc = 0; kc < 4; kc++)
                afr[rt][kc] = *(const bf16x8*)&xl[(rt * 16 + m) * XL_STRIDE + kc * 16 + q * 4];
        f32x4 acc[2][4];
#pragma unroll
        for (int c = 0; c < 2; c++)
#pragma unroll
            for (int rt = 0; rt < 4; rt++) acc[c][rt] = (f32x4){0.f, 0.f, 0.f, 0.f};
#pragma unroll
        for (int c = 0; c < 2; c++) {
            int f = w * 32 + c * 16 + m;
#pragma unroll
            for (int kc = 0; kc < 4; kc++) {
                bf16x8 bfr = *(const bf16x8*)&Wt[f * WT_STRIDE + kc * 16 + q * 4];
#pragma unroll
                for (int rt = 0; rt < 4; rt++)
                    acc[c][rt] = __builtin_amdgcn_mfma_f32_16x16x32_bf16(afr[rt][kc], bfr,
                                                                         acc[c][rt], 0, 0, 0);
            }
        }
        __syncthreads();  // all waves done reading xl
        uint* outl = xl;  // 64 x 65 packed out tile
#pragma unroll
        for (int rt = 0; rt < 4; rt++) {
#pragma unroll
            for (int c = 0; c < 2; c++) {
                f32x4 a = acc[c][rt];
#pragma unroll
                for (int r = 0; r < 4; r++) {
                    float v = a[r];  // UNSCALED: dinv applied in k_agg1
                    float vn = __shfl_xor(v, 1);
                    if (!(lane & 1)) {
                        int row = rt * 16 + q * 4 + r;
                        int cp = (w * 32 + c * 16 + m) >> 1;
                        outl[row * 65 + cp] = pk(v, vn);
                    }
                }
            }
        }
        __syncthreads();
        for (int p = t; p < 64 * 64; p += 256) {
            int r = p >> 6, cc = p & 63;
            int gr = row0 + r;
            if (gr < N) hs_b[(size_t)gr * 64 + cc] = outl[r * 65 + cc];
        }
    }
}

// ---- AGG1: wave per node, gather-sum bf16 rows, no atomics -----------------
// hs_b rows are UNSCALED h; each neighbor scaled by dinv[src] (lane-parallel
// prefetch of dinv alongside ssrc, broadcast via shfl, add->fma). Self-loop
// contributes dinv_d*h_d into the sum; final: relu(dinv_d*sum + b1).

__global__ __launch_bounds__(256) void k_agg1(const uint* __restrict__ hs_b,
                                              const int* __restrict__ rowptr,
                                              const int* __restrict__ deg,
                                              const int* __restrict__ ssrc,
                                              const float* __restrict__ dinv,
                                              const float2* __restrict__ b1, int N,
                                              uint* __restrict__ rh_b) {
    int w = threadIdx.x >> 6, lane = threadIdx.x & 63;
    int d = blockIdx.x * 4 + w;
    if (d >= N) return;
    int start = rowptr[d], cnt = deg[d];
    float sc = dinv[d];
    uint sv = hs_b[(size_t)d * 64 + lane];  // self-loop (unscaled)
    float a0 = bflo(sv) * sc, a1 = bfhi(sv) * sc;
    int base = 0;
    while (base < cnt) {
        int nb = min(cnt - base, 64);
        int idxv = (lane < nb) ? ssrc[start + base + lane] : 0;
        float dvv = dinv[idxv];  // idxv=0 for inactive lanes: valid, unused
        int j = 0;
        for (; j + 16 <= nb; j += 16) {
            uint u[16];
            float dv[16];
#pragma unroll
            for (int q = 0; q < 16; q++) {
                int i = __shfl(idxv, j + q);
                dv[q] = __shfl(dvv, j + q);
                u[q] = hs_b[(size_t)i * 64 + lane];
            }
#pragma unroll
            for (int q = 0; q < 16; q++) {
                a0 = fmaf(bflo(u[q]), dv[q], a0);
                a1 = fmaf(bfhi(u[q]), dv[q], a1);
            }
        }
        for (; j + 4 <= nb; j += 4) {
            uint u[4];
            float dv[4];
#pragma unroll
            for (int q = 0; q < 4; q++) {
                int i = __shfl(idxv, j + q);
                dv[q] = __shfl(dvv, j + q);
                u[q] = hs_b[(size_t)i * 64 + lane];
            }
#pragma unroll
            for (int q = 0; q < 4; q++) {
                a0 = fmaf(bflo(u[q]), dv[q], a0);
                a1 = fmaf(bfhi(u[q]), dv[q], a1);
            }
        }
        for (; j < nb; j++) {
            int i = __shfl(idxv, j);
            float dv = __shfl(dvv, j);
            uint u = hs_b[(size_t)i * 64 + lane];
            a0 = fmaf(bflo(u), dv, a0);
            a1 = fmaf(bfhi(u), dv, a1);
        }
        base += nb;
    }
    float2 bb = b1[lane];
    rh_b[(size_t)d * 64 + lane] =
        pk(fmaxf(fmaf(a0, sc, bb.x), 0.f), fmaxf(fmaf(a1, sc, bb.y), 0.f));
}

// ---- GEMM2: h2_b = bf16( dinv[i] * (rh @ W2) ), one row per thread ---------

__global__ __launch_bounds__(256) void k_gemm2(const uint* __restrict__ rh_b,
                                               const float* __restrict__ W2,
                                               const float* __restrict__ dinv, int N,
                                               uint* __restrict__ h2_b) {
    __shared__ float Wl[D_H * D_OUT];  // 8 KB
    int t = threadIdx.x;
    for (int i = t; i < D_H * D_OUT; i += 256) Wl[i] = W2[i];
    __syncthreads();
    int r = blockIdx.x * 256 + t;
    if (r >= N) return;
    const uint* xrow = rh_b + (size_t)r * 64;
    float acc[16];
#pragma unroll
    for (int f = 0; f < 16; f++) acc[f] = 0.f;
    for (int c = 0; c < 16; c++) {
        uint4 xv = *(const uint4*)(xrow + c * 4);
        uint xs[4] = {xv.x, xv.y, xv.z, xv.w};
#pragma unroll
        for (int u = 0; u < 4; u++) {
            int k = c * 8 + u * 2;
            float x0 = bflo(xs[u]), x1 = bfhi(xs[u]);
            const float* w0 = &Wl[k * 16];
            const float* w1 = &Wl[(k + 1) * 16];
#pragma unroll
            for (int f = 0; f < 16; f++) acc[f] = fmaf(x0, w0[f], acc[f]);
#pragma unroll
            for (int f = 0; f < 16; f++) acc[f] = fmaf(x1, w1[f], acc[f]);
        }
    }
    float sc = dinv[r];
    uint o[8];
#pragma unroll
    for (int q = 0; q < 8; q++) o[q] = pk(acc[2 * q] * sc, acc[2 * q + 1] * sc);
    *(uint4*)&h2_b[(size_t)r * 8] = make_uint4(o[0], o[1], o[2], o[3]);
    *(uint4*)&h2_b[(size_t)r * 8 + 4] = make_uint4(o[4], o[5], o[6], o[7]);
}

// ---- AGG2: wave per node (8 edge slots x 8 uint-features), shfl reduce -----
// Fast path deg<=32 (ng<=4): all 4 group shfls + 4 predicated row loads issued
// back-to-back (MLP 4; masked loads contribute bits 0 == +0.0f). Generic
// wave-uniform loop kept for deg>32. All shfls execute with all lanes active.

__global__ __launch_bounds__(256) void k_agg2(const uint* __restrict__ h2_b,
                                              const int* __restrict__ rowptr,
                                              const int* __restrict__ deg,
                                              const int* __restrict__ ssrc,
                                              const float* __restrict__ dinv,
                                              const float* __restrict__ b2, int N,
                                              float2* __restrict__ out) {
    int w = threadIdx.x >> 6, lane = threadIdx.x & 63;
    int d = blockIdx.x * 4 + w;
    if (d >= N) return;
    int slot = lane >> 3, jp = lane & 7;
    int start = rowptr[d], cnt = deg[d];
    float a0 = 0.f, a1 = 0.f;
    if (slot == 0) {
        uint sv = h2_b[(size_t)d * 8 + jp];  // self-loop
        a0 = bflo(sv);
        a1 = bfhi(sv);
    }
    int base = 0;
    while (base < cnt) {
        int nb = min(cnt - base, 64);
        int idxv = (lane < nb) ? ssrc[start + base + lane] : 0;
        int ng = (nb + 7) >> 3;  // wave-uniform
        if (ng <= 4) {
            int i0 = __shfl(idxv, slot);
            int i1 = __shfl(idxv, 8 + slot);
            int i2 = __shfl(idxv, 16 + slot);
            int i3 = __shfl(idxv, 24 + slot);
            uint u0 = (slot < nb) ? h2_b[(size_t)i0 * 8 + jp] : 0u;
            uint u1 = (8 + slot < nb) ? h2_b[(size_t)i1 * 8 + jp] : 0u;
            uint u2 = (16 + slot < nb) ? h2_b[(size_t)i2 * 8 + jp] : 0u;
            uint u3 = (24 + slot < nb) ? h2_b[(size_t)i3 * 8 + jp] : 0u;
            a0 += bflo(u0) + bflo(u1) + bflo(u2) + bflo(u3);
            a1 += bfhi(u0) + bfhi(u1) + bfhi(u2) + bfhi(u3);
        } else {
            for (int g = 0; g < ng; g++) {
                int j = g * 8 + slot;          // <= 63 always
                int i = __shfl(idxv, j);       // all lanes active here
                if (j < nb) {
                    uint hv = h2_b[(size_t)i * 8 + jp];
                    a0 += bflo(hv);
                    a1 += bfhi(hv);
                }
            }
        }
        base += nb;
    }
    a0 += __shfl_xor(a0, 8);
    a1 += __shfl_xor(a1, 8);
    a0 += __shfl_xor(a0, 16);
    a1 += __shfl_xor(a1, 16);
    a0 += __shfl_xor(a0, 32);
    a1 += __shfl_xor(a1, 32);
    if (slot == 0) {
        float di = dinv[d];
        out[(size_t)d * 8 + jp] =
            make_float2(fmaf(a0, di, b2[2 * jp]), fmaf(a1, di, b2[2 * jp + 1]));
    }
}

// ---- launch ----------------------------------------------------------------

extern "C" void kernel_launch(void* const* d_in, const int* in_sizes, int n_in,
                              void* d_out, int out_size, void* d_ws, size_t ws_size,
                              hipStream_t stream) {
    const float* x  = (const float*)d_in[0];
    const int*   ei = (const int*)d_in[1];
    const float* W1 = (const float*)d_in[2];
    const float* b1 = (const float*)d_in[3];
    const float* W2 = (const float*)d_in[4];
    const float* b2 = (const float*)d_in[5];
    int N = in_sizes[0] / D_IN;
    int E = in_sizes[1] / 2;
    const int* src = ei;
    const int* dst = ei + E;
    int C = (N + NPC - 1) / NPC;           // 196
    int chunk = (E + P1 - 1) / P1;         // 6250
    int ntiles = (N + 63) / 64;            // 1563

    char* ws = (char*)d_ws;
    size_t off = 0;
    auto alloc = [&](size_t bytes) -> char* {
        char* p = ws + off;
        off = (off + bytes + 255) & ~(size_t)255;
        return p;
    };
    int*   hist1   = (int*)alloc((size_t)P1 * C * 4);
    int*   cbase   = (int*)alloc((size_t)(C + 1) * 4);
    uint*  binned1 = (uint*)alloc((size_t)E * 4);
    int*   ssrc    = (int*)alloc((size_t)E * 4);
    int*   rowptr  = (int*)alloc((size_t)N * 4);
    int*   deg     = (int*)alloc((size_t)N * 4);
    float* dinv    = (float*)alloc((size_t)N * 4);
    uint*  W1p     = (uint*)alloc((size_t)64 * 128 * 4);    // 32 KB packed W1
    uint*  hs_b    = (uint*)alloc((size_t)N * 64 * 4);      // 25.6 MB bf16-packed
    uint*  rh_b    = (uint*)alloc((size_t)N * 64 * 4);
    uint*  h2_b    = hs_b;  // hs_b dead after k_agg1; reuse

    k_p1hist<<<P1 + 32, 256, 0, stream>>>(dst, E, N, C, chunk, hist1, W1, W1p);
    k_p1scan<<<1, 1024, 0, stream>>>(hist1, C, cbase);
    k_p1fill<<<P1, 256, 0, stream>>>(src, dst, E, N, C, chunk, hist1, binned1);
    int g1 = min(768, ntiles);
    k_p2gemm1<<<C + g1, 256, 0, stream>>>(binned1, cbase, N, C, ssrc, rowptr, deg, dinv,
                                          W1p, x, hs_b, ntiles);
    k_agg1<<<(N + 3) / 4, 256, 0, stream>>>(hs_b, rowptr, deg, ssrc, dinv,
                                            (const float2*)b1, N, rh_b);
    k_gemm2<<<(N + 255) / 256, 256, 0, stream>>>(rh_b, W2, dinv, N, h2_b);
    k_agg2<<<(N + 3) / 4, 256, 0, stream>>>(h2_b, rowptr, deg, ssrc, dinv, b2, N,
                                            (float2*)d_out);
}